// Round 1
// baseline (2989.284 us; speedup 1.0000x reference)
//
#include <hip/hip_runtime.h>
#include <math.h>

#define D_DIM 3072
#define H_DIM 1024
#define Z_DIM 32
#define BATCH 128
#define NNEI 32
#define NROWS (BATCH * NNEI) /* 4096 */

enum { MODE_BIAS = 0, MODE_RELU = 1, MODE_MASK = 2, MODE_LOSS = 3 };

// Generic 128x128 tiled SGEMM, BK=8, 8x8 per thread (2x2 quadrants of 4).
// A: MxK row-major, B: KxN row-major. Requires M % 128 == 0, K % 8 == 0.
// N may be any size (B loads / C stores guarded).
// MODE_BIAS: C = A@B + bias
// MODE_RELU: C = relu(A@B + bias)
// MODE_MASK: C = (aux1[row>>5, col] > 0) ? A@B : 0      (no bias)
// MODE_LOSS: atomicAdd(out, sum(w[row] * (aux1[row,col] - aux2[row>>5,col] - A@B)^2) / 4096)
template <int MODE>
__global__ __launch_bounds__(256) void gemm128(
    const float* __restrict__ A, const float* __restrict__ B,
    const float* __restrict__ bias, float* __restrict__ C,
    int M, int N, int K,
    const float* __restrict__ aux1, const float* __restrict__ aux2,
    const float* __restrict__ wrow, float* __restrict__ out) {
  __shared__ float As[8][132];
  __shared__ float Bs[8][132];
  const int t = threadIdx.x;
  const int tx = t & 15;
  const int ty = t >> 4;
  const int bm = blockIdx.y * 128;
  const int bn = blockIdx.x * 128;

  float acc[8][8];
#pragma unroll
  for (int i = 0; i < 8; ++i)
#pragma unroll
    for (int j = 0; j < 8; ++j) acc[i][j] = 0.f;

  const int a_row = t >> 1;        // 0..127
  const int a_kq = (t & 1) * 4;    // 0 or 4
  const int b_r = t >> 5;          // 0..7
  const int b_c4 = (t & 31) * 4;   // 0..124

  for (int k0 = 0; k0 < K; k0 += 8) {
    __syncthreads();
    // A tile: rows bm..bm+127, cols k0..k0+7 (always in bounds), store transposed
    {
      const float4 av = *(const float4*)(A + (size_t)(bm + a_row) * K + k0 + a_kq);
      As[a_kq + 0][a_row] = av.x;
      As[a_kq + 1][a_row] = av.y;
      As[a_kq + 2][a_row] = av.z;
      As[a_kq + 3][a_row] = av.w;
    }
    // B tile: rows k0..k0+7, cols bn..bn+127 (col guarded)
    {
      const int col = bn + b_c4;
      if (col + 3 < N) {
        *(float4*)&Bs[b_r][b_c4] = *(const float4*)(B + (size_t)(k0 + b_r) * N + col);
      } else {
#pragma unroll
        for (int j = 0; j < 4; ++j)
          Bs[b_r][b_c4 + j] = (col + j < N) ? B[(size_t)(k0 + b_r) * N + col + j] : 0.f;
      }
    }
    __syncthreads();
#pragma unroll
    for (int k = 0; k < 8; ++k) {
      float a[8], b[8];
      *(float4*)&a[0] = *(const float4*)&As[k][ty * 4];
      *(float4*)&a[4] = *(const float4*)&As[k][64 + ty * 4];
      *(float4*)&b[0] = *(const float4*)&Bs[k][tx * 4];
      *(float4*)&b[4] = *(const float4*)&Bs[k][64 + tx * 4];
#pragma unroll
      for (int i = 0; i < 8; ++i)
#pragma unroll
        for (int j = 0; j < 8; ++j) acc[i][j] = fmaf(a[i], b[j], acc[i][j]);
    }
  }

  if (MODE == MODE_LOSS) {
    // Fused loss epilogue: residual vs x_nn (aux1) and recon (aux2), weighted.
    float lsum = 0.f;
#pragma unroll
    for (int i = 0; i < 8; ++i) {
      const int row = bm + ((i < 4) ? (ty * 4 + i) : (64 + ty * 4 + (i - 4)));
      const int bb = row >> 5;
      const float wv = wrow[row];
      const float* xr = aux1 + (size_t)row * N + bn;
      const float* rr = aux2 + (size_t)bb * N + bn;
      float rs = 0.f;
#pragma unroll
      for (int j = 0; j < 8; ++j) {
        const int c = (j < 4) ? (tx * 4 + j) : (64 + tx * 4 + (j - 4));
        const float r = xr[c] - rr[c] - acc[i][j];
        rs = fmaf(r, r, rs);
      }
      lsum = fmaf(wv, rs, lsum);
    }
    __syncthreads();
    float* red = &As[0][0];
    red[t] = lsum;
    __syncthreads();
    for (int s = 128; s > 0; s >>= 1) {
      if (t < s) red[t] += red[t + s];
      __syncthreads();
    }
    if (t == 0) atomicAdd(out, red[0] * (1.0f / (float)NROWS));
  } else {
#pragma unroll
    for (int i = 0; i < 8; ++i) {
      const int row = bm + ((i < 4) ? (ty * 4 + i) : (64 + ty * 4 + (i - 4)));
#pragma unroll
      for (int j = 0; j < 8; ++j) {
        const int col = bn + ((j < 4) ? (tx * 4 + j) : (64 + tx * 4 + (j - 4)));
        if (col < N) {
          float v = acc[i][j];
          if (MODE == MODE_BIAS || MODE == MODE_RELU) v += bias[col];
          if (MODE == MODE_RELU) v = fmaxf(v, 0.f);
          if (MODE == MODE_MASK) v = (aux1[(size_t)(row >> 5) * N + col] > 0.f) ? v : 0.f;
          C[(size_t)row * N + col] = v;
        }
      }
    }
  }
}

// Per-(b,n) binary kernel weight from ||x_c[b] - x_nn[b,n]||; block 0 also zeroes out[0].
__global__ __launch_bounds__(256) void weight_kernel(
    const float* __restrict__ x_c, const float* __restrict__ x_nn,
    float* __restrict__ w, float* __restrict__ out) {
  const int i = blockIdx.x;  // 0..4095
  const int b = i >> 5;
  const float* xc = x_c + (size_t)b * D_DIM;
  const float* xn = x_nn + (size_t)i * D_DIM;
  float s = 0.f;
  for (int d = threadIdx.x; d < D_DIM; d += 256) {
    const float diff = xc[d] - xn[d];
    s = fmaf(diff, diff, s);
  }
  __shared__ float red[256];
  red[threadIdx.x] = s;
  __syncthreads();
  for (int st = 128; st > 0; st >>= 1) {
    if (threadIdx.x < st) red[threadIdx.x] += red[threadIdx.x + st];
    __syncthreads();
  }
  if (threadIdx.x == 0) {
    w[i] = (sqrtf(red[0]) > 1e-12f) ? 1.0f : 0.5f;
    if (i == 0) out[0] = 0.f;
  }
}

// V[i,:] = z_nn[i,:] - z_c[i>>5,:]
__global__ __launch_bounds__(256) void v_kernel(
    const float* __restrict__ z_nn, const float* __restrict__ z_c,
    float* __restrict__ V) {
  const int idx = blockIdx.x * 256 + threadIdx.x;
  if (idx < NROWS * Z_DIM) {
    const int i = idx >> 5;   // row in [0,4096)
    const int zd = idx & 31;
    const int b = i >> 5;
    V[idx] = z_nn[idx] - z_c[b * Z_DIM + zd];
  }
}

extern "C" void kernel_launch(void* const* d_in, const int* in_sizes, int n_in,
                              void* d_out, int out_size, void* d_ws, size_t ws_size,
                              hipStream_t stream) {
  const float* x_c = (const float*)d_in[0];
  const float* x_nn = (const float*)d_in[1];
  const float* We1 = (const float*)d_in[2];
  const float* be1 = (const float*)d_in[3];
  const float* We2 = (const float*)d_in[4];
  const float* be2 = (const float*)d_in[5];
  const float* We3 = (const float*)d_in[6];
  const float* be3 = (const float*)d_in[7];
  const float* Wd1 = (const float*)d_in[8];
  const float* bd1 = (const float*)d_in[9];
  const float* Wd2 = (const float*)d_in[10];
  const float* bd2 = (const float*)d_in[11];
  const float* Wd3 = (const float*)d_in[12];
  const float* bd3 = (const float*)d_in[13];
  float* out = (float*)d_out;

  float* ws = (float*)d_ws;
  float* bufA = ws;                      // 4096x1024: enc h1 (x_nn), later t1m
  float* bufB = bufA + 4096 * 1024;      // 4096x1024: enc h2 (x_nn), later t2m
  float* z_nn = bufB + 4096 * 1024;      // 4096x32
  float* z_c = z_nn + NROWS * Z_DIM;     // 128x32
  float* h1c = z_c + BATCH * Z_DIM;      // 128x1024
  float* h2c = h1c + BATCH * H_DIM;      // 128x1024
  float* Vb = h2c + BATCH * H_DIM;       // 4096x32
  float* hd1 = Vb + NROWS * Z_DIM;       // 128x1024 (decoder h1 at z_c)
  float* hd2 = hd1 + BATCH * H_DIM;      // 128x1024 (decoder h2 at z_c)
  float* reconb = hd2 + BATCH * H_DIM;   // 128x3072
  float* wbuf = reconb + BATCH * D_DIM;  // 4096

  const dim3 blk(256);

  // weights + zero the output accumulator
  weight_kernel<<<dim3(NROWS), blk, 0, stream>>>(x_c, x_nn, wbuf, out);

  // encoder on x_nn (4096 rows)
  gemm128<MODE_RELU><<<dim3(8, 32), blk, 0, stream>>>(
      x_nn, We1, be1, bufA, NROWS, H_DIM, D_DIM, nullptr, nullptr, nullptr, nullptr);
  gemm128<MODE_RELU><<<dim3(8, 32), blk, 0, stream>>>(
      bufA, We2, be2, bufB, NROWS, H_DIM, H_DIM, nullptr, nullptr, nullptr, nullptr);
  gemm128<MODE_BIAS><<<dim3(1, 32), blk, 0, stream>>>(
      bufB, We3, be3, z_nn, NROWS, Z_DIM, H_DIM, nullptr, nullptr, nullptr, nullptr);

  // encoder on x_c (128 rows)
  gemm128<MODE_RELU><<<dim3(8, 1), blk, 0, stream>>>(
      x_c, We1, be1, h1c, BATCH, H_DIM, D_DIM, nullptr, nullptr, nullptr, nullptr);
  gemm128<MODE_RELU><<<dim3(8, 1), blk, 0, stream>>>(
      h1c, We2, be2, h2c, BATCH, H_DIM, H_DIM, nullptr, nullptr, nullptr, nullptr);
  gemm128<MODE_BIAS><<<dim3(1, 1), blk, 0, stream>>>(
      h2c, We3, be3, z_c, BATCH, Z_DIM, H_DIM, nullptr, nullptr, nullptr, nullptr);

  // tangents V = z_nn - z_c
  v_kernel<<<dim3((NROWS * Z_DIM + 255) / 256), blk, 0, stream>>>(z_nn, z_c, Vb);

  // decoder primal at z_c (also produces masks via relu'd activations)
  gemm128<MODE_RELU><<<dim3(8, 1), blk, 0, stream>>>(
      z_c, Wd1, bd1, hd1, BATCH, H_DIM, Z_DIM, nullptr, nullptr, nullptr, nullptr);
  gemm128<MODE_RELU><<<dim3(8, 1), blk, 0, stream>>>(
      hd1, Wd2, bd2, hd2, BATCH, H_DIM, H_DIM, nullptr, nullptr, nullptr, nullptr);
  gemm128<MODE_BIAS><<<dim3(24, 1), blk, 0, stream>>>(
      hd2, Wd3, bd3, reconb, BATCH, D_DIM, H_DIM, nullptr, nullptr, nullptr, nullptr);

  // JVP chain (ReLU MLP => exact; second-order term is identically zero)
  gemm128<MODE_MASK><<<dim3(8, 32), blk, 0, stream>>>(
      Vb, Wd1, nullptr, bufA, NROWS, H_DIM, Z_DIM, hd1, nullptr, nullptr, nullptr);
  gemm128<MODE_MASK><<<dim3(8, 32), blk, 0, stream>>>(
      bufA, Wd2, nullptr, bufB, NROWS, H_DIM, H_DIM, hd2, nullptr, nullptr, nullptr);
  // final GEMM fused with the weighted-SSE loss reduction
  gemm128<MODE_LOSS><<<dim3(24, 32), blk, 0, stream>>>(
      bufB, Wd3, nullptr, nullptr, NROWS, D_DIM, H_DIM, x_nn, reconb, wbuf, out);
}

// Round 2
// 586.048 us; speedup vs baseline: 5.1007x; 5.1007x over previous
//
#include <hip/hip_runtime.h>
#include <math.h>

#define D_DIM 3072
#define H_DIM 1024
#define Z_DIM 32
#define BATCH 128
#define NNEI 32
#define NROWS (BATCH * NNEI) /* 4096 */
#define MENC (NROWS + BATCH) /* 4224 */

typedef __attribute__((ext_vector_type(8))) short short8;
typedef __attribute__((ext_vector_type(4))) float f32x4;

__device__ __forceinline__ unsigned short f2bf(float f) {
  union { float f; unsigned int u; } v; v.f = f;
  unsigned int r = v.u + 0x7FFFu + ((v.u >> 16) & 1u);
  return (unsigned short)(r >> 16);
}

// async 16B/lane global->LDS. LDS dest is wave-uniform base + lane*16; we pass
// base + lane*16 so lane0's value IS the base (correct under readfirstlane).
__device__ __forceinline__ void gld_lds16(const unsigned short* g, unsigned short* l) {
  __builtin_amdgcn_global_load_lds(
      (const __attribute__((address_space(1))) unsigned int*)g,
      (__attribute__((address_space(3))) unsigned int*)l, 16, 0, 0);
}

enum { EP_RELU = 0, EP_BIAS = 1, EP_MASK = 2, EP_LOSS = 3 };

// bf16 MFMA GEMM, C = epilogue(A @ B), A: MxK bf16 row-major, BT: NxK bf16
// (B transposed). 128x128 tile, BK=32, 4 waves in 2x2, each 64x64 via 4x4
// mfma_f32_16x16x32_bf16. LDS in fragment order: chunk c (16 rows) holds
// [(c*4+quad)*16 + m]*8 contiguous bf16 -> lane reads its 16B at base+lane*16,
// conflict-free ds_read_b128, and global_load_lds fills it directly.
// Requires M%128==0, K%32==0; N arbitrary (guarded).
template <int MODE, int STORE_F32>
__global__ __launch_bounds__(256) void gemm_bf16(
    const unsigned short* __restrict__ A,
    const unsigned short* __restrict__ BT,
    const float* __restrict__ bias,
    void* __restrict__ Cv,
    int M, int N, int K,
    const unsigned short* __restrict__ mask,  // (MODE_MASK) 128 x N bf16, >0 passes
    const float* __restrict__ aux1,           // (MODE_LOSS) x_nn, M x N f32
    const float* __restrict__ aux2,           // (MODE_LOSS) recon, 128 x N f32
    const float* __restrict__ wrow,           // (MODE_LOSS) per-row weight
    float* __restrict__ out) {
  __shared__ unsigned short As[4096];  // 8 KB
  __shared__ unsigned short Bs[4096];  // 8 KB
  __shared__ float red[256];

  const int t = threadIdx.x;
  const int wave = t >> 6;
  const int lane = t & 63;
  const int quad = lane >> 4;
  const int lm = lane & 15;
  const int bm = blockIdx.y * 128;
  const int bn = blockIdx.x * 128;
  const int wr = (wave >> 1) * 64;  // wave row offset in tile
  const int wc = (wave & 1) * 64;   // wave col offset in tile

  f32x4 acc[4][4];
#pragma unroll
  for (int i = 0; i < 4; ++i)
#pragma unroll
    for (int j = 0; j < 4; ++j) acc[i][j] = (f32x4)0.f;

  // staging: wave handles chunks {2w, 2w+1} of both A and B tiles
  const int c0 = wave * 2;
  const unsigned short* aptr0 = A + (size_t)(bm + c0 * 16 + lm) * K + quad * 8;
  const unsigned short* aptr1 = aptr0 + (size_t)16 * K;
  int br0 = bn + c0 * 16 + lm;      if (br0 > N - 1) br0 = N - 1;
  int br1 = bn + c0 * 16 + 16 + lm; if (br1 > N - 1) br1 = N - 1;
  const unsigned short* bptr0 = BT + (size_t)br0 * K + quad * 8;
  const unsigned short* bptr1 = BT + (size_t)br1 * K + quad * 8;
  unsigned short* asd0 = As + c0 * 512 + lane * 8;
  unsigned short* asd1 = asd0 + 512;
  unsigned short* bsd0 = Bs + c0 * 512 + lane * 8;
  unsigned short* bsd1 = bsd0 + 512;

  const unsigned short* afb = As + (wr >> 4) * 512 + lane * 8;
  const unsigned short* bfb = Bs + (wc >> 4) * 512 + lane * 8;

  for (int k0 = 0; k0 < K; k0 += 32) {
    __syncthreads();
    gld_lds16(aptr0, asd0);
    gld_lds16(aptr1, asd1);
    gld_lds16(bptr0, bsd0);
    gld_lds16(bptr1, bsd1);
    aptr0 += 32; aptr1 += 32; bptr0 += 32; bptr1 += 32;
    __syncthreads();  // compiler emits vmcnt(0) drain here

    short8 af[4], bf[4];
#pragma unroll
    for (int i = 0; i < 4; ++i) {
      af[i] = *(const short8*)(afb + i * 512);
      bf[i] = *(const short8*)(bfb + i * 512);
    }
#pragma unroll
    for (int mt = 0; mt < 4; ++mt)
#pragma unroll
      for (int nt = 0; nt < 4; ++nt)
        acc[mt][nt] = __builtin_amdgcn_mfma_f32_16x16x32_bf16(af[mt], bf[nt], acc[mt][nt], 0, 0, 0);
  }

  // C/D layout: col = lane&15, row = quad*4 + reg
  if (MODE == EP_LOSS) {
    float lsum = 0.f;
#pragma unroll
    for (int mt = 0; mt < 4; ++mt) {
#pragma unroll
      for (int r = 0; r < 4; ++r) {
        const int row = bm + wr + mt * 16 + quad * 4 + r;
        const float w = wrow[row];
        const float* xr = aux1 + (size_t)row * N;
        const float* rr = aux2 + (size_t)(row >> 5) * N;
        float rs = 0.f;
#pragma unroll
        for (int nt = 0; nt < 4; ++nt) {
          const int col = bn + wc + nt * 16 + lm;
          const float d = xr[col] - rr[col] - acc[mt][nt][r];
          rs = fmaf(d, d, rs);
        }
        lsum = fmaf(w, rs, lsum);
      }
    }
    __syncthreads();
    red[t] = lsum;
    __syncthreads();
    for (int s = 128; s > 0; s >>= 1) {
      if (t < s) red[t] += red[t + s];
      __syncthreads();
    }
    if (t == 0) atomicAdd(out, red[0] * (1.0f / (float)NROWS));
  } else {
#pragma unroll
    for (int mt = 0; mt < 4; ++mt) {
#pragma unroll
      for (int r = 0; r < 4; ++r) {
        const int row = bm + wr + mt * 16 + quad * 4 + r;
#pragma unroll
        for (int nt = 0; nt < 4; ++nt) {
          const int col = bn + wc + nt * 16 + lm;
          if (col < N) {
            float v = acc[mt][nt][r];
            if (MODE == EP_RELU || MODE == EP_BIAS) v += bias[col];
            if (MODE == EP_RELU) v = fmaxf(v, 0.f);
            if (MODE == EP_MASK) {
              const short mb = (short)mask[(size_t)(row >> 5) * N + col];
              if (mb <= 0) v = 0.f;
            }
            if (STORE_F32) ((float*)Cv)[(size_t)row * N + col] = v;
            else ((unsigned short*)Cv)[(size_t)row * N + col] = f2bf(v);
          }
        }
      }
    }
  }
}

// W: K x N fp32 -> WT: N x K bf16 (dims multiples of 32)
__global__ __launch_bounds__(256) void transpose_bf16(
    const float* __restrict__ W, unsigned short* __restrict__ WT, int K, int N) {
  __shared__ float tile[32][33];
  const int n0 = blockIdx.x * 32;
  const int k0 = blockIdx.y * 32;
  const int tx = threadIdx.x & 31;
  const int ty = threadIdx.x >> 5;
  for (int i = ty; i < 32; i += 8)
    tile[i][tx] = W[(size_t)(k0 + i) * N + n0 + tx];
  __syncthreads();
  for (int i = ty; i < 32; i += 8)
    WT[(size_t)(n0 + i) * K + k0 + tx] = f2bf(tile[tx][i]);
}

__global__ __launch_bounds__(256) void cvt_bf16(
    const float* __restrict__ x, unsigned short* __restrict__ y, int n) {
  const int i = (blockIdx.x * 256 + threadIdx.x) * 4;
  if (i + 3 < n) {
    const float4 v = *(const float4*)(x + i);
    ushort4 o;
    o.x = f2bf(v.x); o.y = f2bf(v.y); o.z = f2bf(v.z); o.w = f2bf(v.w);
    *(ushort4*)(y + i) = o;
  }
}

// weights from ||x_c[b]-x_nn[b,n]||; block 0 zeroes out[0]
__global__ __launch_bounds__(256) void weight_kernel(
    const float* __restrict__ x_c, const float* __restrict__ x_nn,
    float* __restrict__ w, float* __restrict__ out) {
  const int i = blockIdx.x;
  const int b = i >> 5;
  const float* xc = x_c + (size_t)b * D_DIM;
  const float* xn = x_nn + (size_t)i * D_DIM;
  float s = 0.f;
  for (int d = threadIdx.x; d < D_DIM; d += 256) {
    const float diff = xc[d] - xn[d];
    s = fmaf(diff, diff, s);
  }
  __shared__ float red[256];
  red[threadIdx.x] = s;
  __syncthreads();
  for (int st = 128; st > 0; st >>= 1) {
    if (threadIdx.x < st) red[threadIdx.x] += red[threadIdx.x + st];
    __syncthreads();
  }
  if (threadIdx.x == 0) {
    w[i] = (sqrtf(red[0]) > 1e-12f) ? 1.0f : 0.5f;
    if (i == 0) out[0] = 0.f;
  }
}

// V = z_nn - z_c (fp32 diff -> bf16); also emit z_c as bf16
__global__ __launch_bounds__(256) void v_kernel(
    const float* __restrict__ z, unsigned short* __restrict__ V,
    unsigned short* __restrict__ zc) {
  const int idx = blockIdx.x * 256 + threadIdx.x;
  if (idx < NROWS * Z_DIM) {
    const int b = idx >> 10;  // (idx>>5)>>5
    const int zd = idx & 31;
    V[idx] = f2bf(z[idx] - z[(size_t)(NROWS + b) * Z_DIM + zd]);
  }
  if (idx < BATCH * Z_DIM) zc[idx] = f2bf(z[(size_t)NROWS * Z_DIM + idx]);
}

extern "C" void kernel_launch(void* const* d_in, const int* in_sizes, int n_in,
                              void* d_out, int out_size, void* d_ws, size_t ws_size,
                              hipStream_t stream) {
  const float* x_c = (const float*)d_in[0];
  const float* x_nn = (const float*)d_in[1];
  const float* We1 = (const float*)d_in[2];
  const float* be1 = (const float*)d_in[3];
  const float* We2 = (const float*)d_in[4];
  const float* be2 = (const float*)d_in[5];
  const float* We3 = (const float*)d_in[6];
  const float* be3 = (const float*)d_in[7];
  const float* Wd1 = (const float*)d_in[8];
  const float* bd1 = (const float*)d_in[9];
  const float* Wd2 = (const float*)d_in[10];
  const float* bd2 = (const float*)d_in[11];
  const float* Wd3 = (const float*)d_in[12];
  const float* bd3 = (const float*)d_in[13];
  float* out = (float*)d_out;

  char* p = (char*)d_ws;
  auto alloc = [&](size_t bytes) {
    char* r = p;
    p += (bytes + 63) & ~(size_t)63;
    return r;
  };
  unsigned short* We1T = (unsigned short*)alloc((size_t)H_DIM * D_DIM * 2);
  unsigned short* We2T = (unsigned short*)alloc((size_t)H_DIM * H_DIM * 2);
  unsigned short* We3T = (unsigned short*)alloc((size_t)Z_DIM * H_DIM * 2);
  unsigned short* Wd1T = (unsigned short*)alloc((size_t)H_DIM * Z_DIM * 2);
  unsigned short* Wd2T = (unsigned short*)alloc((size_t)H_DIM * H_DIM * 2);
  unsigned short* Wd3T = (unsigned short*)alloc((size_t)D_DIM * H_DIM * 2);
  unsigned short* A_enc = (unsigned short*)alloc((size_t)MENC * D_DIM * 2);
  unsigned short* h1 = (unsigned short*)alloc((size_t)MENC * H_DIM * 2);  // later t1
  unsigned short* h2 = (unsigned short*)alloc((size_t)MENC * H_DIM * 2);  // later t2
  float* z = (float*)alloc((size_t)MENC * Z_DIM * 4);
  unsigned short* V = (unsigned short*)alloc((size_t)NROWS * Z_DIM * 2);
  unsigned short* zc = (unsigned short*)alloc((size_t)BATCH * Z_DIM * 2);
  unsigned short* hd1 = (unsigned short*)alloc((size_t)BATCH * H_DIM * 2);
  unsigned short* hd2 = (unsigned short*)alloc((size_t)BATCH * H_DIM * 2);
  float* recon = (float*)alloc((size_t)BATCH * D_DIM * 4);
  float* wbuf = (float*)alloc((size_t)NROWS * 4);

  const dim3 blk(256);

  // weights + zero loss accumulator
  weight_kernel<<<dim3(NROWS), blk, 0, stream>>>(x_c, x_nn, wbuf, out);

  // bf16 conversions (x) and transposed bf16 weights
  cvt_bf16<<<dim3((NROWS * D_DIM) / 1024), blk, 0, stream>>>(x_nn, A_enc, NROWS * D_DIM);
  cvt_bf16<<<dim3((BATCH * D_DIM) / 1024), blk, 0, stream>>>(x_c, A_enc + (size_t)NROWS * D_DIM, BATCH * D_DIM);
  transpose_bf16<<<dim3(H_DIM / 32, D_DIM / 32), blk, 0, stream>>>(We1, We1T, D_DIM, H_DIM);
  transpose_bf16<<<dim3(H_DIM / 32, H_DIM / 32), blk, 0, stream>>>(We2, We2T, H_DIM, H_DIM);
  transpose_bf16<<<dim3(Z_DIM / 32, H_DIM / 32), blk, 0, stream>>>(We3, We3T, H_DIM, Z_DIM);
  transpose_bf16<<<dim3(H_DIM / 32, Z_DIM / 32), blk, 0, stream>>>(Wd1, Wd1T, Z_DIM, H_DIM);
  transpose_bf16<<<dim3(H_DIM / 32, H_DIM / 32), blk, 0, stream>>>(Wd2, Wd2T, H_DIM, H_DIM);
  transpose_bf16<<<dim3(D_DIM / 32, H_DIM / 32), blk, 0, stream>>>(Wd3, Wd3T, H_DIM, D_DIM);

  // encoder on [x_nn; x_c] (4224 rows)
  gemm_bf16<EP_RELU, 0><<<dim3(8, 33), blk, 0, stream>>>(
      A_enc, We1T, be1, h1, MENC, H_DIM, D_DIM, nullptr, nullptr, nullptr, nullptr, nullptr);
  gemm_bf16<EP_RELU, 0><<<dim3(8, 33), blk, 0, stream>>>(
      h1, We2T, be2, h2, MENC, H_DIM, H_DIM, nullptr, nullptr, nullptr, nullptr, nullptr);
  gemm_bf16<EP_BIAS, 1><<<dim3(1, 33), blk, 0, stream>>>(
      h2, We3T, be3, z, MENC, Z_DIM, H_DIM, nullptr, nullptr, nullptr, nullptr, nullptr);

  // tangents V = z_nn - z_c (fp32 subtract), z_c -> bf16
  v_kernel<<<dim3((NROWS * Z_DIM + 255) / 256), blk, 0, stream>>>(z, V, zc);

  // decoder primal at z_c (produces relu masks hd1, hd2 and recon)
  gemm_bf16<EP_RELU, 0><<<dim3(8, 1), blk, 0, stream>>>(
      zc, Wd1T, bd1, hd1, BATCH, H_DIM, Z_DIM, nullptr, nullptr, nullptr, nullptr, nullptr);
  gemm_bf16<EP_RELU, 0><<<dim3(8, 1), blk, 0, stream>>>(
      hd1, Wd2T, bd2, hd2, BATCH, H_DIM, H_DIM, nullptr, nullptr, nullptr, nullptr, nullptr);
  gemm_bf16<EP_BIAS, 1><<<dim3(24, 1), blk, 0, stream>>>(
      hd2, Wd3T, bd3, recon, BATCH, D_DIM, H_DIM, nullptr, nullptr, nullptr, nullptr, nullptr);

  // JVP chain (ReLU MLP => exact; 2nd-order term identically zero)
  unsigned short* t1 = h1;
  unsigned short* t2 = h2;
  gemm_bf16<EP_MASK, 0><<<dim3(8, 32), blk, 0, stream>>>(
      V, Wd1T, nullptr, t1, NROWS, H_DIM, Z_DIM, hd1, nullptr, nullptr, nullptr, nullptr);
  gemm_bf16<EP_MASK, 0><<<dim3(8, 32), blk, 0, stream>>>(
      t1, Wd2T, nullptr, t2, NROWS, H_DIM, H_DIM, hd2, nullptr, nullptr, nullptr, nullptr);
  // final GEMM fused with weighted-SSE loss reduction
  gemm_bf16<EP_LOSS, 0><<<dim3(24, 32), blk, 0, stream>>>(
      t2, Wd3T, nullptr, nullptr, NROWS, D_DIM, H_DIM, nullptr, x_nn, recon, wbuf, out);
}

// Round 3
// 466.151 us; speedup vs baseline: 6.4127x; 1.2572x over previous
//
#include <hip/hip_runtime.h>
#include <math.h>

#define D_DIM 3072
#define H_DIM 1024
#define Z_DIM 32
#define BATCH 128
#define NNEI 32
#define NROWS (BATCH * NNEI) /* 4096 */
#define MENC (NROWS + BATCH) /* 4224 */

typedef __attribute__((ext_vector_type(8))) short short8;
typedef __attribute__((ext_vector_type(4))) float f32x4;
typedef unsigned short ushortT;

__device__ __forceinline__ unsigned short f2bf(float f) {
  union { float f; unsigned int u; } v; v.f = f;
  unsigned int r = v.u + 0x7FFFu + ((v.u >> 16) & 1u);
  return (unsigned short)(r >> 16);
}
__device__ __forceinline__ float bf2f(unsigned short b) {
  union { unsigned int u; float f; } v; v.u = ((unsigned int)b) << 16;
  return v.f;
}

// async 16B/lane global->LDS (wave-uniform base + lane*16)
__device__ __forceinline__ void gld_lds16(const unsigned short* g, unsigned short* l) {
  __builtin_amdgcn_global_load_lds(
      (const __attribute__((address_space(1))) unsigned int*)g,
      (__attribute__((address_space(3))) unsigned int*)l, 16, 0, 0);
}

enum { EP_RELU = 0, EP_BIAS = 1, EP_MASKB = 2, EP_LOSS = 3 };

// bf16 MFMA GEMM with double-buffered LDS (single barrier per K-iter).
// A: MxK bf16 row-major, BT: NxK bf16. Tile 128 x TN, BK=32, 4 waves in 2x2,
// each wave 64 x TN/2 via mfma_f32_16x16x32_bf16 (acc[4][TN/32]).
// LDS fragment order: chunk c holds rows [c*16, c*16+16), lane layout matches
// the MFMA A/B fragment (16B per lane, conflict-free ds_read_b128) and the
// global_load_lds lane order.
// EP_RELU:  C = relu(acc + bias)
// EP_BIAS:  C = acc + bias
// EP_MASKB: C = (mask[row>>5, col] > 0) ? (acc + bias) : 0
// EP_LOSS:  atomicAdd(out, sum w[row]*(bf2f(xa[row,col]) - (acc+bias[col]))^2 / 4096)
template <int MODE, int TN>
__global__ __launch_bounds__(256) void gemm_bf16(
    const ushortT* __restrict__ A,
    const ushortT* __restrict__ BT,
    const float* __restrict__ bias,
    ushortT* __restrict__ C,
    int M, int N, int K,
    const ushortT* __restrict__ mask,  // EP_MASKB: 128 x N bf16 (center acts)
    const ushortT* __restrict__ xa,    // EP_LOSS: M x N bf16
    const float* __restrict__ wrow,    // EP_LOSS: per-row weight
    float* __restrict__ out) {
  constexpr int NF = TN / 32;  // n-frags per wave
  __shared__ __align__(16) ushortT As[2][4096];
  __shared__ __align__(16) ushortT Bs[2][TN * 32];
  __shared__ float red[256];

  const int t = threadIdx.x;
  const int wave = t >> 6;
  const int lane = t & 63;
  const int quad = lane >> 4;
  const int lm = lane & 15;
  const int bm = blockIdx.y * 128;
  const int bn = blockIdx.x * TN;
  const int wr = (wave >> 1) * 64;
  const int wc = (wave & 1) * (TN / 2);

  f32x4 acc[4][NF];
#pragma unroll
  for (int i = 0; i < 4; ++i)
#pragma unroll
    for (int j = 0; j < NF; ++j) acc[i][j] = (f32x4)0.f;

  // A staging: wave stages chunks {2w, 2w+1} (rows wave*32 .. +31)
  const ushortT* ag0 = A + (size_t)(bm + wave * 32 + lm) * K + quad * 8;
  const ushortT* ag1 = ag0 + (size_t)16 * K;
  // B staging
  const ushortT* bg0;
  const ushortT* bg1 = nullptr;
  if (TN == 128) {
    int r0 = bn + wave * 32 + lm;      if (r0 > N - 1) r0 = N - 1;
    int r1 = bn + wave * 32 + 16 + lm; if (r1 > N - 1) r1 = N - 1;
    bg0 = BT + (size_t)r0 * K + quad * 8;
    bg1 = BT + (size_t)r1 * K + quad * 8;
  } else {
    int r0 = bn + wave * 16 + lm; if (r0 > N - 1) r0 = N - 1;
    bg0 = BT + (size_t)r0 * K + quad * 8;
  }

  auto issue = [&](int k0, int b) {
    gld_lds16(ag0 + k0, &As[b][wave * 1024 + lane * 8]);
    gld_lds16(ag1 + k0, &As[b][wave * 1024 + 512 + lane * 8]);
    if (TN == 128) {
      gld_lds16(bg0 + k0, &Bs[b][wave * 1024 + lane * 8]);
      gld_lds16(bg1 + k0, &Bs[b][wave * 1024 + 512 + lane * 8]);
    } else {
      gld_lds16(bg0 + k0, &Bs[b][wave * 512 + lane * 8]);
    }
  };

  issue(0, 0);
  int buf = 0;
  for (int k0 = 0; k0 < K; k0 += 32) {
    __syncthreads();  // vmcnt drain: buf's tiles are resident; prev reads done
    if (k0 + 32 < K) issue(k0 + 32, buf ^ 1);

    const ushortT* ab = &As[buf][(wr >> 4) * 512 + lane * 8];
    const ushortT* bb = &Bs[buf][(wc >> 4) * 512 + lane * 8];
    short8 af[4], bf[NF];
#pragma unroll
    for (int mt = 0; mt < 4; ++mt) af[mt] = *(const short8*)(ab + mt * 512);
#pragma unroll
    for (int nt = 0; nt < NF; ++nt) bf[nt] = *(const short8*)(bb + nt * 512);
#pragma unroll
    for (int mt = 0; mt < 4; ++mt)
#pragma unroll
      for (int nt = 0; nt < NF; ++nt)
        acc[mt][nt] = __builtin_amdgcn_mfma_f32_16x16x32_bf16(af[mt], bf[nt], acc[mt][nt], 0, 0, 0);
    buf ^= 1;
  }

  // C/D layout: col = lane&15, row = quad*4 + reg
  if (MODE == EP_LOSS) {
    float lsum = 0.f;
#pragma unroll
    for (int mt = 0; mt < 4; ++mt) {
#pragma unroll
      for (int r = 0; r < 4; ++r) {
        const int row = bm + wr + mt * 16 + quad * 4 + r;
        const float w = wrow[row];
        const ushortT* xr = xa + (size_t)row * N;
        float rs = 0.f;
#pragma unroll
        for (int nt = 0; nt < NF; ++nt) {
          const int col = bn + wc + nt * 16 + lm;
          const float d = bf2f(xr[col]) - (acc[mt][nt][r] + bias[col]);
          rs = fmaf(d, d, rs);
        }
        lsum = fmaf(w, rs, lsum);
      }
    }
    __syncthreads();
    red[t] = lsum;
    __syncthreads();
    for (int s = 128; s > 0; s >>= 1) {
      if (t < s) red[t] += red[t + s];
      __syncthreads();
    }
    if (t == 0) atomicAdd(out, red[0] * (1.0f / (float)NROWS));
  } else {
#pragma unroll
    for (int mt = 0; mt < 4; ++mt) {
#pragma unroll
      for (int r = 0; r < 4; ++r) {
        const int row = bm + wr + mt * 16 + quad * 4 + r;
#pragma unroll
        for (int nt = 0; nt < NF; ++nt) {
          const int col = bn + wc + nt * 16 + lm;
          if (col < N) {
            float v = acc[mt][nt][r] + bias[col];
            if (MODE == EP_RELU) v = fmaxf(v, 0.f);
            if (MODE == EP_MASKB) {
              const short mb = (short)mask[(size_t)(row >> 5) * N + col];
              if (mb <= 0) v = 0.f;
            }
            C[(size_t)row * N + col] = f2bf(v);
          }
        }
      }
    }
  }
}

// Fused prep: x_nn/x_c fp32 -> A_enc bf16; per-(b,n) weights from dist^2;
// zeroes out[0]. Grid: 4224 blocks (4096 x_nn rows + 128 x_c rows).
__global__ __launch_bounds__(256) void prep_kernel(
    const float* __restrict__ x_c, const float* __restrict__ x_nn,
    ushortT* __restrict__ A_enc, float* __restrict__ wbuf, float* __restrict__ out) {
  const int i = blockIdx.x;
  const int t = threadIdx.x;
  if (i < NROWS) {
    const float* src = x_nn + (size_t)i * D_DIM;
    const float* ctr = x_c + (size_t)(i >> 5) * D_DIM;
    ushortT* dst = A_enc + (size_t)i * D_DIM;
    float s = 0.f;
    for (int d = t * 4; d < D_DIM; d += 1024) {
      const float4 v = *(const float4*)(src + d);
      const float4 c = *(const float4*)(ctr + d);
      ushort4 o;
      o.x = f2bf(v.x); o.y = f2bf(v.y); o.z = f2bf(v.z); o.w = f2bf(v.w);
      *(ushort4*)(dst + d) = o;
      float dx = v.x - c.x, dy = v.y - c.y, dz = v.z - c.z, dw = v.w - c.w;
      s += dx * dx + dy * dy + dz * dz + dw * dw;
    }
    __shared__ float red[256];
    red[t] = s;
    __syncthreads();
    for (int st = 128; st > 0; st >>= 1) {
      if (t < st) red[t] += red[t + st];
      __syncthreads();
    }
    if (t == 0) {
      wbuf[i] = (red[0] > 1e-24f) ? 1.0f : 0.5f;
      if (i == 0) out[0] = 0.f;
    }
  } else {
    const int r = i - NROWS;
    const float* src = x_c + (size_t)r * D_DIM;
    ushortT* dst = A_enc + (size_t)i * D_DIM;
    for (int d = t * 4; d < D_DIM; d += 1024) {
      const float4 v = *(const float4*)(src + d);
      ushort4 o;
      o.x = f2bf(v.x); o.y = f2bf(v.y); o.z = f2bf(v.z); o.w = f2bf(v.w);
      *(ushort4*)(dst + d) = o;
    }
  }
}

// Batched transpose+cast of all six weights: W (KxN f32) -> WT (NxK bf16).
// 32x32 tiles; block ranges hardcoded.
__global__ __launch_bounds__(256) void trans_all(
    const float* __restrict__ We1, const float* __restrict__ We2,
    const float* __restrict__ We3, const float* __restrict__ Wd1,
    const float* __restrict__ Wd2, const float* __restrict__ Wd3,
    ushortT* __restrict__ We1T, ushortT* __restrict__ We2T,
    ushortT* __restrict__ We3T, ushortT* __restrict__ Wd1T,
    ushortT* __restrict__ Wd2T, ushortT* __restrict__ Wd3T) {
  const int b = blockIdx.x;
  const float* W; ushortT* WT; int K, N, loc;
  if (b < 3072)      { W = We1; WT = We1T; K = 3072; N = 1024; loc = b; }
  else if (b < 4096) { W = We2; WT = We2T; K = 1024; N = 1024; loc = b - 3072; }
  else if (b < 4128) { W = We3; WT = We3T; K = 1024; N = 32;   loc = b - 4096; }
  else if (b < 4160) { W = Wd1; WT = Wd1T; K = 32;   N = 1024; loc = b - 4128; }
  else if (b < 5184) { W = Wd2; WT = Wd2T; K = 1024; N = 1024; loc = b - 4160; }
  else               { W = Wd3; WT = Wd3T; K = 1024; N = 3072; loc = b - 5184; }
  const int ntiles = N >> 5;
  const int n0 = (loc % ntiles) * 32;
  const int k0 = (loc / ntiles) * 32;
  __shared__ float tile[32][33];
  const int tx = threadIdx.x & 31;
  const int ty = threadIdx.x >> 5;
  for (int i = ty; i < 32; i += 8)
    tile[i][tx] = W[(size_t)(k0 + i) * N + n0 + tx];
  __syncthreads();
  for (int i = ty; i < 32; i += 8)
    WT[(size_t)(n0 + i) * K + k0 + tx] = f2bf(tile[tx][i]);
}

extern "C" void kernel_launch(void* const* d_in, const int* in_sizes, int n_in,
                              void* d_out, int out_size, void* d_ws, size_t ws_size,
                              hipStream_t stream) {
  const float* x_c = (const float*)d_in[0];
  const float* x_nn = (const float*)d_in[1];
  const float* We1 = (const float*)d_in[2];
  const float* be1 = (const float*)d_in[3];
  const float* We2 = (const float*)d_in[4];
  const float* be2 = (const float*)d_in[5];
  const float* We3 = (const float*)d_in[6];
  const float* be3 = (const float*)d_in[7];
  const float* Wd1 = (const float*)d_in[8];
  const float* bd1 = (const float*)d_in[9];
  const float* Wd2 = (const float*)d_in[10];
  const float* bd2 = (const float*)d_in[11];
  const float* Wd3 = (const float*)d_in[12];
  const float* bd3 = (const float*)d_in[13];
  float* out = (float*)d_out;

  char* p = (char*)d_ws;
  auto alloc = [&](size_t bytes) {
    char* r = p;
    p += (bytes + 255) & ~(size_t)255;
    return r;
  };
  ushortT* We1T = (ushortT*)alloc((size_t)H_DIM * D_DIM * 2);
  ushortT* We2T = (ushortT*)alloc((size_t)H_DIM * H_DIM * 2);
  ushortT* We3T = (ushortT*)alloc((size_t)Z_DIM * H_DIM * 2);
  ushortT* Wd1T = (ushortT*)alloc((size_t)H_DIM * Z_DIM * 2);
  ushortT* Wd2T = (ushortT*)alloc((size_t)H_DIM * H_DIM * 2);
  ushortT* Wd3T = (ushortT*)alloc((size_t)D_DIM * H_DIM * 2);
  ushortT* A_enc = (ushortT*)alloc((size_t)MENC * D_DIM * 2);
  ushortT* h1 = (ushortT*)alloc((size_t)MENC * H_DIM * 2);  // later t1
  ushortT* h2 = (ushortT*)alloc((size_t)MENC * H_DIM * 2);  // later t2
  ushortT* z = (ushortT*)alloc((size_t)MENC * Z_DIM * 2);
  ushortT* h1c = (ushortT*)alloc((size_t)BATCH * H_DIM * 2);
  ushortT* h2c = (ushortT*)alloc((size_t)BATCH * H_DIM * 2);
  float* wbuf = (float*)alloc((size_t)NROWS * 4);

  const dim3 blk(256);

  // x -> bf16, weights, out zero; all six W -> bf16 transposed
  prep_kernel<<<dim3(MENC), blk, 0, stream>>>(x_c, x_nn, A_enc, wbuf, out);
  trans_all<<<dim3(8256), blk, 0, stream>>>(We1, We2, We3, Wd1, Wd2, Wd3,
                                            We1T, We2T, We3T, Wd1T, Wd2T, Wd3T);

  // encoder on [x_nn; x_c] (4224 rows)
  gemm_bf16<EP_RELU, 64><<<dim3(16, 33), blk, 0, stream>>>(
      A_enc, We1T, be1, h1, MENC, H_DIM, D_DIM, nullptr, nullptr, nullptr, nullptr);
  gemm_bf16<EP_RELU, 64><<<dim3(16, 33), blk, 0, stream>>>(
      h1, We2T, be2, h2, MENC, H_DIM, H_DIM, nullptr, nullptr, nullptr, nullptr);
  gemm_bf16<EP_BIAS, 64><<<dim3(1, 33), blk, 0, stream>>>(
      h2, We3T, be3, z, MENC, Z_DIM, H_DIM, nullptr, nullptr, nullptr, nullptr);

  // center decoder activations (masks): h1c, h2c (128 rows)
  gemm_bf16<EP_RELU, 64><<<dim3(16, 1), blk, 0, stream>>>(
      z + (size_t)NROWS * Z_DIM, Wd1T, bd1, h1c, BATCH, H_DIM, Z_DIM,
      nullptr, nullptr, nullptr, nullptr);
  gemm_bf16<EP_RELU, 64><<<dim3(16, 1), blk, 0, stream>>>(
      h1c, Wd2T, bd2, h2c, BATCH, H_DIM, H_DIM, nullptr, nullptr, nullptr, nullptr);

  // linearized decoder at z_nn with frozen center masks:
  // n_recon = W3^T (m2 .* (W2^T (m1 .* (W1^T z_nn + b1)) + b2)) + b3
  //         = recon + J dz   (exact for ReLU MLP; 2nd-order term = 0)
  ushortT* t1 = h1;
  ushortT* t2 = h2;
  gemm_bf16<EP_MASKB, 64><<<dim3(16, 32), blk, 0, stream>>>(
      z, Wd1T, bd1, t1, NROWS, H_DIM, Z_DIM, h1c, nullptr, nullptr, nullptr);
  gemm_bf16<EP_MASKB, 64><<<dim3(16, 32), blk, 0, stream>>>(
      t1, Wd2T, bd2, t2, NROWS, H_DIM, H_DIM, h2c, nullptr, nullptr, nullptr);
  // final GEMM fused with weighted-SSE loss (residual vs bf16 x_nn)
  gemm_bf16<EP_LOSS, 128><<<dim3(24, 32), blk, 0, stream>>>(
      t2, Wd3T, bd3, nullptr, NROWS, D_DIM, H_DIM, nullptr, A_enc, wbuf, out);
}

// Round 4
// 453.191 us; speedup vs baseline: 6.5961x; 1.0286x over previous
//
#include <hip/hip_runtime.h>
#include <math.h>

#define D_DIM 3072
#define H_DIM 1024
#define Z_DIM 32
#define BATCH 128
#define NNEI 32
#define NROWS (BATCH * NNEI) /* 4096 */
#define MENC (NROWS + BATCH) /* 4224 */

typedef __attribute__((ext_vector_type(8))) short short8;
typedef __attribute__((ext_vector_type(4))) float f32x4;
typedef unsigned short ushortT;

__device__ __forceinline__ unsigned short f2bf(float f) {
  union { float f; unsigned int u; } v; v.f = f;
  unsigned int r = v.u + 0x7FFFu + ((v.u >> 16) & 1u);
  return (unsigned short)(r >> 16);
}
__device__ __forceinline__ float bf2f(unsigned short b) {
  union { unsigned int u; float f; } v; v.u = ((unsigned int)b) << 16;
  return v.f;
}

// async 16B/lane global->LDS (wave-uniform base + lane*16)
__device__ __forceinline__ void gld_lds16(const unsigned short* g, unsigned short* l) {
  __builtin_amdgcn_global_load_lds(
      (const __attribute__((address_space(1))) unsigned int*)g,
      (__attribute__((address_space(3))) unsigned int*)l, 16, 0, 0);
}

enum { EP_RELU = 0, EP_BIAS = 1, EP_PART = 2, EP_LOSS = 3 };

// bf16 MFMA GEMM, tile TM x TN, BK=32, double-buffered LDS, 4 waves in 2x2
// (wave tile TM/2 x TN/2). A: MxK bf16 row-major, BT: NxK bf16.
// grid = (N/TN, M/TM, S); split s covers K range [s*Ks, s*Ks+Ks).
// LDS fragment order: chunk c holds rows [c*16,c*16+16) in MFMA lane order
// (16B/lane, conflict-free ds_read_b128, matches global_load_lds lane order).
// EP_RELU: C=relu(acc+bias) bf16   EP_BIAS: C=acc+bias bf16
// EP_PART: P[s]=acc fp32 (no bias)
// EP_LOSS: atomicAdd(out, sum w[row]*(bf2f(xa[row,col])-(acc+bias[col]))^2/4096)
template <int MODE, int TM, int TN>
__global__ __launch_bounds__(256) void gemm_bf16(
    const ushortT* __restrict__ A, const ushortT* __restrict__ BT,
    const float* __restrict__ bias, ushortT* __restrict__ C,
    float* __restrict__ P, int M, int N, int K, int Ks,
    const ushortT* __restrict__ xa, const float* __restrict__ wrow,
    float* __restrict__ out) {
  constexpr int MF = TM / 32;  // m-frags per wave
  constexpr int NF = TN / 32;  // n-frags per wave
  constexpr int CA = TM / 16;  // A chunks per stage
  constexpr int CB = TN / 16;  // B chunks per stage
  constexpr int APW = CA / 4;  // A chunks staged per wave (>=1)
  constexpr int BPW = (CB >= 4) ? (CB / 4) : 1;

  __shared__ __align__(16) ushortT As[2][TM * 32];
  __shared__ __align__(16) ushortT Bs[2][TN * 32];
  __shared__ float red[256];

  const int t = threadIdx.x;
  const int wave = t >> 6;
  const int lane = t & 63;
  const int quad = lane >> 4;
  const int lm = lane & 15;
  const int bm = blockIdx.y * TM;
  const int bn = blockIdx.x * TN;
  const int sp = blockIdx.z;
  const int wr = (wave >> 1) * (TM / 2);
  const int wc = (wave & 1) * (TN / 2);

  f32x4 acc[MF][NF];
#pragma unroll
  for (int i = 0; i < MF; ++i)
#pragma unroll
    for (int j = 0; j < NF; ++j) acc[i][j] = (f32x4)0.f;

  const ushortT* agp[APW];
  ushortT* asd[2][APW];
#pragma unroll
  for (int i = 0; i < APW; ++i) {
    const int c = wave * APW + i;
    agp[i] = A + (size_t)(bm + c * 16 + lm) * K + (size_t)sp * Ks + quad * 8;
    asd[0][i] = &As[0][c * 512 + lane * 8];
    asd[1][i] = &As[1][c * 512 + lane * 8];
  }
  const ushortT* bgp[BPW];
  ushortT* bsd[2][BPW];
#pragma unroll
  for (int i = 0; i < BPW; ++i) {
    const int c = (CB >= 4) ? (wave * BPW + i) : ((wave < CB) ? wave : 0);
    bgp[i] = BT + (size_t)(bn + c * 16 + lm) * K + (size_t)sp * Ks + quad * 8;
    bsd[0][i] = &Bs[0][c * 512 + lane * 8];
    bsd[1][i] = &Bs[1][c * 512 + lane * 8];
  }
  const bool bactive = (CB >= 4) || (wave < CB);

  auto issue = [&](int k0, int b) {
#pragma unroll
    for (int i = 0; i < APW; ++i) gld_lds16(agp[i] + k0, asd[b][i]);
    if (bactive) {
#pragma unroll
      for (int i = 0; i < BPW; ++i) gld_lds16(bgp[i] + k0, bsd[b][i]);
    }
  };

  issue(0, 0);
  int buf = 0;
  for (int k0 = 0; k0 < Ks; k0 += 32) {
    __syncthreads();  // vmcnt drain: buf resident; prev reads done
    if (k0 + 32 < Ks) issue(k0 + 32, buf ^ 1);

    const ushortT* ab = &As[buf][(wr >> 4) * 512 + lane * 8];
    const ushortT* bb = &Bs[buf][(wc >> 4) * 512 + lane * 8];
    short8 af[MF], bf[NF];
#pragma unroll
    for (int mt = 0; mt < MF; ++mt) af[mt] = *(const short8*)(ab + mt * 512);
#pragma unroll
    for (int nt = 0; nt < NF; ++nt) bf[nt] = *(const short8*)(bb + nt * 512);
#pragma unroll
    for (int mt = 0; mt < MF; ++mt)
#pragma unroll
      for (int nt = 0; nt < NF; ++nt)
        acc[mt][nt] = __builtin_amdgcn_mfma_f32_16x16x32_bf16(af[mt], bf[nt], acc[mt][nt], 0, 0, 0);
    buf ^= 1;
  }

  // C/D layout: col = lane&15, row = quad*4 + reg
  if (MODE == EP_LOSS) {
    float lsum = 0.f;
#pragma unroll
    for (int mt = 0; mt < MF; ++mt) {
#pragma unroll
      for (int r = 0; r < 4; ++r) {
        const int row = bm + wr + mt * 16 + quad * 4 + r;
        const float w = wrow[row];
        const ushortT* xr = xa + (size_t)row * N;
        float rs = 0.f;
#pragma unroll
        for (int nt = 0; nt < NF; ++nt) {
          const int col = bn + wc + nt * 16 + lm;
          const float d = bf2f(xr[col]) - (acc[mt][nt][r] + bias[col]);
          rs = fmaf(d, d, rs);
        }
        lsum = fmaf(w, rs, lsum);
      }
    }
    __syncthreads();
    red[t] = lsum;
    __syncthreads();
    for (int st = 128; st > 0; st >>= 1) {
      if (t < st) red[t] += red[t + st];
      __syncthreads();
    }
    if (t == 0) atomicAdd(out, red[0] * (1.0f / (float)NROWS));
  } else if (MODE == EP_PART) {
#pragma unroll
    for (int mt = 0; mt < MF; ++mt)
#pragma unroll
      for (int r = 0; r < 4; ++r) {
        const int row = bm + wr + mt * 16 + quad * 4 + r;
#pragma unroll
        for (int nt = 0; nt < NF; ++nt) {
          const int col = bn + wc + nt * 16 + lm;
          P[((size_t)sp * M + row) * N + col] = acc[mt][nt][r];
        }
      }
  } else {
#pragma unroll
    for (int mt = 0; mt < MF; ++mt)
#pragma unroll
      for (int r = 0; r < 4; ++r) {
        const int row = bm + wr + mt * 16 + quad * 4 + r;
#pragma unroll
        for (int nt = 0; nt < NF; ++nt) {
          const int col = bn + wc + nt * 16 + lm;
          float v = acc[mt][nt][r] + bias[col];
          if (MODE == EP_RELU) v = fmaxf(v, 0.f);
          C[(size_t)row * N + col] = f2bf(v);
        }
      }
  }
}

// sum split-K fp32 partials + bias (+relu) -> bf16. N power of 2.
template <int S, bool RELU>
__global__ __launch_bounds__(256) void reduce_lin(
    const float* __restrict__ P, const float* __restrict__ bias,
    ushortT* __restrict__ outp, int MN, int Nmask) {
  const int i4 = (blockIdx.x * 256 + threadIdx.x) * 4;
  if (i4 >= MN) return;
  float4 s = *(const float4*)(P + i4);
#pragma unroll
  for (int k = 1; k < S; ++k) {
    const float4 q = *(const float4*)(P + (size_t)k * MN + i4);
    s.x += q.x; s.y += q.y; s.z += q.z; s.w += q.w;
  }
  const float4 b = *(const float4*)(bias + (i4 & Nmask));
  s.x += b.x; s.y += b.y; s.z += b.z; s.w += b.w;
  if (RELU) {
    s.x = fmaxf(s.x, 0.f); s.y = fmaxf(s.y, 0.f);
    s.z = fmaxf(s.z, 0.f); s.w = fmaxf(s.w, 0.f);
  }
  ushort4 o;
  o.x = f2bf(s.x); o.y = f2bf(s.y); o.z = f2bf(s.z); o.w = f2bf(s.w);
  *(ushort4*)(outp + i4) = o;
}

// Frozen-mask apply on raw pre-activations U (MENC x 1024 bf16):
// rows < 4096 (neighbors): out = (U[center_row] > 0) ? U : 0
// rows >= 4096 (centers, if covered by grid): out = relu(U)
__global__ __launch_bounds__(256) void mask_apply(
    const ushortT* __restrict__ U, ushortT* __restrict__ outp) {
  const int i4 = (blockIdx.x * 256 + threadIdx.x) * 4;
  const int r = i4 >> 10;
  const int c = i4 & 1023;
  ushort4 u = *(const ushort4*)(U + i4);
  ushort4 o;
  if (r < NROWS) {
    const ushort4 m = *(const ushort4*)(U + (((size_t)(NROWS + (r >> 5))) << 10) + c);
    o.x = ((short)m.x > 0) ? u.x : 0;
    o.y = ((short)m.y > 0) ? u.y : 0;
    o.z = ((short)m.z > 0) ? u.z : 0;
    o.w = ((short)m.w > 0) ? u.w : 0;
  } else {
    o.x = ((short)u.x > 0) ? u.x : 0;
    o.y = ((short)u.y > 0) ? u.y : 0;
    o.z = ((short)u.z > 0) ? u.z : 0;
    o.w = ((short)u.w > 0) ? u.w : 0;
  }
  *(ushort4*)(outp + i4) = o;
}

// Fused prep: x fp32 -> bf16 A_enc; per-(b,n) weights from dist^2; zero out[0].
__global__ __launch_bounds__(256) void prep_kernel(
    const float* __restrict__ x_c, const float* __restrict__ x_nn,
    ushortT* __restrict__ A_enc, float* __restrict__ wbuf, float* __restrict__ out) {
  const int i = blockIdx.x;
  const int t = threadIdx.x;
  if (i < NROWS) {
    const float* src = x_nn + (size_t)i * D_DIM;
    const float* ctr = x_c + (size_t)(i >> 5) * D_DIM;
    ushortT* dst = A_enc + (size_t)i * D_DIM;
    float s = 0.f;
    for (int d = t * 4; d < D_DIM; d += 1024) {
      const float4 v = *(const float4*)(src + d);
      const float4 c = *(const float4*)(ctr + d);
      ushort4 o;
      o.x = f2bf(v.x); o.y = f2bf(v.y); o.z = f2bf(v.z); o.w = f2bf(v.w);
      *(ushort4*)(dst + d) = o;
      const float dx = v.x - c.x, dy = v.y - c.y, dz = v.z - c.z, dw = v.w - c.w;
      s += dx * dx + dy * dy + dz * dz + dw * dw;
    }
    __shared__ float red[256];
    red[t] = s;
    __syncthreads();
    for (int st = 128; st > 0; st >>= 1) {
      if (t < st) red[t] += red[t + st];
      __syncthreads();
    }
    if (t == 0) {
      wbuf[i] = (red[0] > 1e-24f) ? 1.0f : 0.5f;
      if (i == 0) out[0] = 0.f;
    }
  } else {
    const int r = i - NROWS;
    const float* src = x_c + (size_t)r * D_DIM;
    ushortT* dst = A_enc + (size_t)i * D_DIM;
    for (int d = t * 4; d < D_DIM; d += 1024) {
      const float4 v = *(const float4*)(src + d);
      ushort4 o;
      o.x = f2bf(v.x); o.y = f2bf(v.y); o.z = f2bf(v.z); o.w = f2bf(v.w);
      *(ushort4*)(dst + d) = o;
    }
  }
}

// Batched transpose+cast of all six weights: W (KxN f32) -> WT (NxK bf16).
__global__ __launch_bounds__(256) void trans_all(
    const float* __restrict__ We1, const float* __restrict__ We2,
    const float* __restrict__ We3, const float* __restrict__ Wd1,
    const float* __restrict__ Wd2, const float* __restrict__ Wd3,
    ushortT* __restrict__ We1T, ushortT* __restrict__ We2T,
    ushortT* __restrict__ We3T, ushortT* __restrict__ Wd1T,
    ushortT* __restrict__ Wd2T, ushortT* __restrict__ Wd3T) {
  const int b = blockIdx.x;
  const float* W; ushortT* WT; int K, N, loc;
  if (b < 3072)      { W = We1; WT = We1T; K = 3072; N = 1024; loc = b; }
  else if (b < 4096) { W = We2; WT = We2T; K = 1024; N = 1024; loc = b - 3072; }
  else if (b < 4128) { W = We3; WT = We3T; K = 1024; N = 32;   loc = b - 4096; }
  else if (b < 4160) { W = Wd1; WT = Wd1T; K = 32;   N = 1024; loc = b - 4128; }
  else if (b < 5184) { W = Wd2; WT = Wd2T; K = 1024; N = 1024; loc = b - 4160; }
  else               { W = Wd3; WT = Wd3T; K = 1024; N = 3072; loc = b - 5184; }
  const int ntiles = N >> 5;
  const int n0 = (loc % ntiles) * 32;
  const int k0 = (loc / ntiles) * 32;
  __shared__ float tile[32][33];
  const int tx = threadIdx.x & 31;
  const int ty = threadIdx.x >> 5;
  for (int i = ty; i < 32; i += 8)
    tile[i][tx] = W[(size_t)(k0 + i) * N + n0 + tx];
  __syncthreads();
  for (int i = ty; i < 32; i += 8)
    WT[(size_t)(n0 + i) * K + k0 + tx] = f2bf(tile[tx][i]);
}

extern "C" void kernel_launch(void* const* d_in, const int* in_sizes, int n_in,
                              void* d_out, int out_size, void* d_ws, size_t ws_size,
                              hipStream_t stream) {
  const float* x_c = (const float*)d_in[0];
  const float* x_nn = (const float*)d_in[1];
  const float* We1 = (const float*)d_in[2];
  const float* be1 = (const float*)d_in[3];
  const float* We2 = (const float*)d_in[4];
  const float* be2 = (const float*)d_in[5];
  const float* We3 = (const float*)d_in[6];
  const float* be3 = (const float*)d_in[7];
  const float* Wd1 = (const float*)d_in[8];
  const float* bd1 = (const float*)d_in[9];
  const float* Wd2 = (const float*)d_in[10];
  const float* bd2 = (const float*)d_in[11];
  const float* Wd3 = (const float*)d_in[12];
  const float* bd3 = (const float*)d_in[13];
  float* out = (float*)d_out;

  char* p = (char*)d_ws;
  auto alloc = [&](size_t bytes) {
    char* r = p;
    p += (bytes + 255) & ~(size_t)255;
    return r;
  };
  ushortT* We1T = (ushortT*)alloc((size_t)H_DIM * D_DIM * 2);
  ushortT* We2T = (ushortT*)alloc((size_t)H_DIM * H_DIM * 2);
  ushortT* We3T = (ushortT*)alloc((size_t)Z_DIM * H_DIM * 2);
  ushortT* Wd1T = (ushortT*)alloc((size_t)H_DIM * Z_DIM * 2);
  ushortT* Wd2T = (ushortT*)alloc((size_t)H_DIM * H_DIM * 2);
  ushortT* Wd3T = (ushortT*)alloc((size_t)D_DIM * H_DIM * 2);
  ushortT* A_enc = (ushortT*)alloc((size_t)MENC * D_DIM * 2);
  ushortT* bufX = (ushortT*)alloc((size_t)MENC * H_DIM * 2);  // h1 / U1 / U2
  ushortT* bufY = (ushortT*)alloc((size_t)MENC * H_DIM * 2);  // h2 / A2 / t2
  ushortT* z = (ushortT*)alloc((size_t)MENC * Z_DIM * 2);
  float* Pz = (float*)alloc((size_t)8 * MENC * Z_DIM * 4);
  float* wbuf = (float*)alloc((size_t)NROWS * 4);

  const dim3 blk(256);
  const float* nofp = nullptr;
  const ushortT* nobf = nullptr;

  // x -> bf16, per-neighbor weights, zero loss accumulator; weights -> bf16^T
  prep_kernel<<<dim3(MENC), blk, 0, stream>>>(x_c, x_nn, A_enc, wbuf, out);
  trans_all<<<dim3(8256), blk, 0, stream>>>(We1, We2, We3, Wd1, Wd2, Wd3,
                                            We1T, We2T, We3T, Wd1T, Wd2T, Wd3T);

  // encoder on [x_nn; x_c] (4224 rows), 64x64 tiles -> 1056 blocks (~4/CU)
  gemm_bf16<EP_RELU, 64, 64><<<dim3(16, 66, 1), blk, 0, stream>>>(
      A_enc, We1T, be1, bufX, nullptr, MENC, H_DIM, D_DIM, D_DIM, nobf, nofp, nullptr);
  gemm_bf16<EP_RELU, 64, 64><<<dim3(16, 66, 1), blk, 0, stream>>>(
      bufX, We2T, be2, bufY, nullptr, MENC, H_DIM, H_DIM, H_DIM, nobf, nofp, nullptr);
  // z = h2 @ We3 + be3 (skinny N=32): split-K S=8 -> 528 blocks
  gemm_bf16<EP_PART, 64, 32><<<dim3(1, 66, 8), blk, 0, stream>>>(
      bufY, We3T, nofp, nullptr, Pz, MENC, Z_DIM, H_DIM, H_DIM / 8, nobf, nofp, nullptr);
  reduce_lin<8, false><<<dim3((MENC * Z_DIM) / 1024), blk, 0, stream>>>(
      Pz, be3, z, MENC * Z_DIM, Z_DIM - 1);

  // linearized decoder with frozen center masks (exact for ReLU MLP):
  // U1 = [z_nn; z_c] @ Wd1 + bd1 (raw, all rows)
  gemm_bf16<EP_BIAS, 64, 128><<<dim3(8, 66, 1), blk, 0, stream>>>(
      z, Wd1T, bd1, bufX, nullptr, MENC, H_DIM, Z_DIM, Z_DIM, nobf, nofp, nullptr);
  // A2 = mask1 .* U1 (neighbors), relu(U1) (centers)
  mask_apply<<<dim3((MENC * H_DIM) / 1024), blk, 0, stream>>>(bufX, bufY);
  // U2 = A2 @ Wd2 + bd2 (raw, all rows)
  gemm_bf16<EP_BIAS, 64, 64><<<dim3(16, 66, 1), blk, 0, stream>>>(
      bufY, Wd2T, bd2, bufX, nullptr, MENC, H_DIM, H_DIM, H_DIM, nobf, nofp, nullptr);
  // t2 = mask2 .* U2 (neighbor rows only)
  mask_apply<<<dim3((NROWS * H_DIM) / 1024), blk, 0, stream>>>(bufX, bufY);
  // loss GEMM: pred = t2 @ Wd3 + bd3, fused weighted-SSE vs bf16 x_nn
  gemm_bf16<EP_LOSS, 64, 128><<<dim3(24, 64, 1), blk, 0, stream>>>(
      bufY, Wd3T, bd3, nullptr, nullptr, NROWS, D_DIM, H_DIM, H_DIM, A_enc, wbuf, out);
}